// Round 11
// baseline (25.032 us; speedup 1.0000x reference)
//
#include <hip/hip_runtime.h>
#include <hip/hip_bf16.h>

#define CIN 32
#define HW 64
#define KK 64
#define NLEAF 8
#define PADDING 2
#define TR 8                    // tile rows
#define TC 16                   // tile cols
#define WR 12                   // window rows = TR + 4
#define WC 20                   // window cols = TC + 4
#define WPOS (CIN * WR * WC)    // 7680 positions; f32x2 each -> 61440 B LDS

typedef float f32x2 __attribute__((ext_vector_type(2)));

__device__ __constant__ float d_C[16][4] = {
    {0, 0, 0, 0},  {0, 0, 0, 1},  {0, 1, 0, -1}, {0, 1, 0, 0},
    {0, 0, 1, -1}, {0, 0, 1, 0},  {0, 1, 1, -2}, {0, 1, 1, -1},
    {1, -1, -1, 1},{1, -1, -1, 2},{1, 0, -1, 0}, {1, 0, -1, 1},
    {1, -1, 0, 0}, {1, -1, 0, 1}, {1, 0, 0, -1}, {1, 0, 0, 0}
};

// blocks 0..3: coefA[k*60 + node*4 + c]; block 4: loffA[k*16+n] = ELEMENT
// offset of leaf (c,dh,dw) in the f32x2-interleaved 32 x 12 x 20 window.
__global__ __launch_bounds__(256) void prep_kernel(
    const int* __restrict__ idx_h, const int* __restrict__ idx_w, const int* __restrict__ idx_c,
    const float* __restrict__ w0, const float* __restrict__ w1,
    const float* __restrict__ w2, const float* __restrict__ w3,
    float* __restrict__ coefA, int* __restrict__ loffA)
{
    if (blockIdx.x == 4) {
        int k = threadIdx.x;
        if (k < KK) {
            #pragma unroll
            for (int n = 0; n < 16; ++n) {
                int s = n >> 3, leaf = n & 7;
                int o = s * (KK * NLEAF) + k * NLEAF + leaf;
                loffA[k * 16 + n] = idx_c[o] * (WR * WC) + idx_h[o] * WC + idx_w[o];
            }
        }
        return;
    }
    int t = blockIdx.x * blockDim.x + threadIdx.x;
    if (t >= KK * 15) return;
    int k = t / 15, node = t % 15;
    const float* wp; int n;
    if (node < 8)       { wp = w0; n = node; }
    else if (node < 12) { wp = w1; n = node - 8; }
    else if (node < 14) { wp = w2; n = node - 12; }
    else                { wp = w3; n = 0; }
    const float* l = wp + (n * KK + k) * 16;
    float m = l[0];
    #pragma unroll
    for (int g = 1; g < 16; ++g) m = fmaxf(m, l[g]);
    float p[16], s = 0.f;
    #pragma unroll
    for (int g = 0; g < 16; ++g) { p[g] = expf(l[g] - m); s += p[g]; }
    float inv = 1.f / s;
    float c0 = 0, c1 = 0, c2 = 0, c3 = 0;
    #pragma unroll
    for (int g = 0; g < 16; ++g) {
        float w = p[g] * inv;
        c0 = fmaf(w, d_C[g][0], c0);
        c1 = fmaf(w, d_C[g][1], c1);
        c2 = fmaf(w, d_C[g][2], c2);
        c3 = fmaf(w, d_C[g][3], c3);
    }
    float* o = coefA + (k * 60 + node * 4);
    o[0] = c0; o[1] = c1; o[2] = c2; o[3] = c3;
}

__device__ __forceinline__ f32x2 bc(float s) { return (f32x2){s, s}; }
__device__ __forceinline__ f32x2 gate2(const float* c, f32x2 a, f32x2 b) {
    return __builtin_elementwise_fma(b,
               __builtin_elementwise_fma(a, bc(c[3]), bc(c[2])),
               __builtin_elementwise_fma(a, bc(c[1]), bc(c[0])));
}

// blockIdx = (kg*32 + tile)*8 + bp  (XCD-pinned by bp). 512 threads = 8 waves.
// Tile = 8x16 px; wave w handles k = kg*16 + 2w + {0,1}; per k it loops 2
// pixel sub-tiles (4x16 each) whose LDS addresses differ by an immediate
// (+80 elements = offset:640), so the inner loop has ZERO uniform fetches.
// lane = pixel of the 4x16 sub-tile; f32x2 = 2 batch images.
__global__ __launch_bounds__(512, 4) void logic_conv_kernel(
    const float* __restrict__ x, const int* __restrict__ loffA,
    const float* __restrict__ coefA, float* __restrict__ out)
{
    __shared__ f32x2 xt[WPOS];

    int tid = threadIdx.x;
    int bp  = blockIdx.x & 7;          // batch-pair == XCD slot
    int rem = blockIdx.x >> 3;
    int t   = rem & 31;                // tile 0..31 (8 row-tiles x 4 col-tiles)
    int kg  = rem >> 5;                // k-group 0..3
    int r0  = (t >> 2) * TR;
    int c0  = (t & 3) * TC;

    const float* xb0 = x + (size_t)(2 * bp) * (CIN * HW * HW);
    const float* xb1 = xb0 + (CIN * HW * HW);

    // Stage interleaved padded 32x12x20 windows (15 positions/thread).
    #pragma unroll
    for (int i = 0; i < 15; ++i) {
        int e  = tid + i * 512;
        int c  = e / (WR * WC);
        int r  = e - c * (WR * WC);
        int rr = r / WC;
        int cc = r - rr * WC;
        int ih = r0 + rr - PADDING, iw = c0 + cc - PADDING;
        f32x2 v = {0.f, 0.f};
        if ((unsigned)ih < HW && (unsigned)iw < HW) {
            int go = (c * HW + ih) * HW + iw;
            v.x = xb0[go];
            v.y = xb1[go];
        }
        xt[e] = v;
    }
    __syncthreads();

    int lane = tid & 63, wave = tid >> 6;
    int tr = lane >> 4, tc = lane & 15;
    int pxe   = tr * WC + tc;                  // element offset in window
    int pxout = (r0 + tr) * HW + (c0 + tc);    // output element offset
    float* outB0 = out + ((size_t)(2 * bp) << 18);
    float* outB1 = outB0 + (1 << 18);

    int kbase = __builtin_amdgcn_readfirstlane(kg * 16 + wave * 2);

    #pragma unroll
    for (int p = 0; p < 2; ++p) {
        int k = kbase + p;
        const int*   L = loffA + (k << 4);
        const float* C = coefA + k * 60;

        #pragma unroll
        for (int it = 0; it < 2; ++it) {
            f32x2 g[16];
            #pragma unroll
            for (int n = 0; n < 16; ++n)
                g[n] = xt[L[n] + pxe + it * (4 * WC)];   // +80 elems -> offset:640

            f32x2 v[8];
            #pragma unroll
            for (int n = 0; n < 8; ++n)
                v[n] = gate2(C + 4 * n, g[n], g[8 + n]);
            f32x2 u[4];
            #pragma unroll
            for (int n = 0; n < 4; ++n)
                u[n] = gate2(C + 32 + 4 * n, v[2 * n], v[2 * n + 1]);
            f32x2 t0 = gate2(C + 48, u[0], u[1]);
            f32x2 t1 = gate2(C + 52, u[2], u[3]);
            f32x2 r  = gate2(C + 56, t0, t1);

            int ko = (k << 12) + pxout + it * (4 * HW);
            __builtin_nontemporal_store(r.x, &outB0[ko]);
            __builtin_nontemporal_store(r.y, &outB1[ko]);
        }
    }
}

extern "C" void kernel_launch(void* const* d_in, const int* in_sizes, int n_in,
                              void* d_out, int out_size, void* d_ws, size_t ws_size,
                              hipStream_t stream) {
    const float* x     = (const float*)d_in[0];
    const int*   idx_h = (const int*)d_in[1];
    const int*   idx_w = (const int*)d_in[2];
    const int*   idx_c = (const int*)d_in[3];
    const float* w0    = (const float*)d_in[4];
    const float* w1    = (const float*)d_in[5];
    const float* w2    = (const float*)d_in[6];
    const float* w3    = (const float*)d_in[7];
    float* out   = (float*)d_out;

    float* coefA = (float*)d_ws;                      // 15,360 B
    int*   loffA = (int*)((char*)d_ws + 16384);       // 4,096 B

    hipLaunchKernelGGL(prep_kernel, dim3(5), dim3(256), 0, stream,
                       idx_h, idx_w, idx_c, w0, w1, w2, w3, coefA, loffA);
    // 4 k-groups * 32 tiles * 8 batch-pairs = 1024 blocks, XCD-pinned by bp
    hipLaunchKernelGGL(logic_conv_kernel, dim3(1024), dim3(512), 0, stream,
                       x, loffA, coefA, out);
}

// Round 12
// 24.161 us; speedup vs baseline: 1.0361x; 1.0361x over previous
//
#include <hip/hip_runtime.h>
#include <hip/hip_bf16.h>

#define CIN 32
#define HW 64
#define KK 64
#define NLEAF 8
#define PADDING 2
#define TR 8                    // tile rows
#define TC 16                   // tile cols
#define WR 12                   // window rows = TR + 4
#define WC 20                   // window cols = TC + 4
#define WPOS (CIN * WR * WC)    // 7680 positions; f32x2 each -> 61440 B LDS

typedef float f32x2 __attribute__((ext_vector_type(2)));

__device__ __constant__ float d_C[16][4] = {
    {0, 0, 0, 0},  {0, 0, 0, 1},  {0, 1, 0, -1}, {0, 1, 0, 0},
    {0, 0, 1, -1}, {0, 0, 1, 0},  {0, 1, 1, -2}, {0, 1, 1, -1},
    {1, -1, -1, 1},{1, -1, -1, 2},{1, 0, -1, 0}, {1, 0, -1, 1},
    {1, -1, 0, 0}, {1, -1, 0, 1}, {1, 0, 0, -1}, {1, 0, 0, 0}
};

// blocks 0..3: coefA[k*60 + node*4 + c]; block 4: loffA[k*16+n] = ELEMENT
// offset of leaf (c,dh,dw) in the f32x2-interleaved 32 x 12 x 20 window.
__global__ __launch_bounds__(256) void prep_kernel(
    const int* __restrict__ idx_h, const int* __restrict__ idx_w, const int* __restrict__ idx_c,
    const float* __restrict__ w0, const float* __restrict__ w1,
    const float* __restrict__ w2, const float* __restrict__ w3,
    float* __restrict__ coefA, int* __restrict__ loffA)
{
    if (blockIdx.x == 4) {
        int k = threadIdx.x;
        if (k < KK) {
            #pragma unroll
            for (int n = 0; n < 16; ++n) {
                int s = n >> 3, leaf = n & 7;
                int o = s * (KK * NLEAF) + k * NLEAF + leaf;
                loffA[k * 16 + n] = idx_c[o] * (WR * WC) + idx_h[o] * WC + idx_w[o];
            }
        }
        return;
    }
    int t = blockIdx.x * blockDim.x + threadIdx.x;
    if (t >= KK * 15) return;
    int k = t / 15, node = t % 15;
    const float* wp; int n;
    if (node < 8)       { wp = w0; n = node; }
    else if (node < 12) { wp = w1; n = node - 8; }
    else if (node < 14) { wp = w2; n = node - 12; }
    else                { wp = w3; n = 0; }
    const float* l = wp + (n * KK + k) * 16;
    float m = l[0];
    #pragma unroll
    for (int g = 1; g < 16; ++g) m = fmaxf(m, l[g]);
    float p[16], s = 0.f;
    #pragma unroll
    for (int g = 0; g < 16; ++g) { p[g] = expf(l[g] - m); s += p[g]; }
    float inv = 1.f / s;
    float c0 = 0, c1 = 0, c2 = 0, c3 = 0;
    #pragma unroll
    for (int g = 0; g < 16; ++g) {
        float w = p[g] * inv;
        c0 = fmaf(w, d_C[g][0], c0);
        c1 = fmaf(w, d_C[g][1], c1);
        c2 = fmaf(w, d_C[g][2], c2);
        c3 = fmaf(w, d_C[g][3], c3);
    }
    float* o = coefA + (k * 60 + node * 4);
    o[0] = c0; o[1] = c1; o[2] = c2; o[3] = c3;
}

__device__ __forceinline__ f32x2 bc(float s) { return (f32x2){s, s}; }
__device__ __forceinline__ f32x2 gate2(const float* c, f32x2 a, f32x2 b) {
    return __builtin_elementwise_fma(b,
               __builtin_elementwise_fma(a, bc(c[3]), bc(c[2])),
               __builtin_elementwise_fma(a, bc(c[1]), bc(c[0])));
}

// blockIdx = (kg*32 + tile)*8 + bp (XCD-pinned by bp; staging of the same
// window by both kg groups hits that XCD's L2). 512 threads = 8 waves.
// Tile = 8x16 px; wave w handles k = kg*32 + 4w + {0..3}; per k each lane
// computes 2 pixels (rows tr and tr+4) whose LDS addresses differ by 640 B,
// loaded adjacently so they merge into ds_read2_b64. f32x2 = 2 batch images.
__global__ __launch_bounds__(512, 4) void logic_conv_kernel(
    const float* __restrict__ x, const int* __restrict__ loffA,
    const float* __restrict__ coefA, float* __restrict__ out)
{
    __shared__ f32x2 xt[WPOS];

    int tid = threadIdx.x;
    int bp  = blockIdx.x & 7;          // batch-pair == XCD slot
    int rem = blockIdx.x >> 3;
    int t   = rem & 31;                // tile 0..31 (8 row-tiles x 4 col-tiles)
    int kg  = rem >> 5;                // k-group 0..1
    int r0  = (t >> 2) * TR;
    int c0  = (t & 3) * TC;

    const float* xb0 = x + (size_t)(2 * bp) * (CIN * HW * HW);
    const float* xb1 = xb0 + (CIN * HW * HW);

    // Stage interleaved padded 32x12x20 windows (15 positions/thread).
    #pragma unroll
    for (int i = 0; i < 15; ++i) {
        int e  = tid + i * 512;
        int c  = e / (WR * WC);
        int r  = e - c * (WR * WC);
        int rr = r / WC;
        int cc = r - rr * WC;
        int ih = r0 + rr - PADDING, iw = c0 + cc - PADDING;
        f32x2 v = {0.f, 0.f};
        if ((unsigned)ih < HW && (unsigned)iw < HW) {
            int go = (c * HW + ih) * HW + iw;
            v.x = xb0[go];
            v.y = xb1[go];
        }
        xt[e] = v;
    }
    __syncthreads();

    int lane = tid & 63, wave = tid >> 6;
    int tr = lane >> 4, tc = lane & 15;
    int pxe   = tr * WC + tc;                  // element offset in window
    int pxout = (r0 + tr) * HW + (c0 + tc);    // output element offset (px0)
    float* outB0 = out + ((size_t)(2 * bp) << 18);
    float* outB1 = outB0 + (1 << 18);

    int kbase = __builtin_amdgcn_readfirstlane(kg * 32 + wave * 4);

    #pragma unroll 2
    for (int i = 0; i < 4; ++i) {
        int k = kbase + i;
        const int*   L = loffA + (k << 4);
        const float* C = coefA + k * 60;

        // paired gathers: px0 and px1 (4 rows apart = +80 elements = 640 B)
        f32x2 g0[16], g1[16];
        #pragma unroll
        for (int n = 0; n < 16; ++n) {
            const f32x2* p = &xt[L[n] + pxe];
            g0[n] = p[0];
            g1[n] = p[80];
        }

        f32x2 v0[8], v1[8];
        #pragma unroll
        for (int n = 0; n < 8; ++n) {
            v0[n] = gate2(C + 4 * n, g0[n], g0[8 + n]);
            v1[n] = gate2(C + 4 * n, g1[n], g1[8 + n]);
        }
        f32x2 u0[4], u1[4];
        #pragma unroll
        for (int n = 0; n < 4; ++n) {
            u0[n] = gate2(C + 32 + 4 * n, v0[2 * n], v0[2 * n + 1]);
            u1[n] = gate2(C + 32 + 4 * n, v1[2 * n], v1[2 * n + 1]);
        }
        f32x2 s00 = gate2(C + 48, u0[0], u0[1]);
        f32x2 s01 = gate2(C + 52, u0[2], u0[3]);
        f32x2 s10 = gate2(C + 48, u1[0], u1[1]);
        f32x2 s11 = gate2(C + 52, u1[2], u1[3]);
        f32x2 q0  = gate2(C + 56, s00, s01);
        f32x2 q1  = gate2(C + 56, s10, s11);

        int ko = (k << 12) + pxout;
        __builtin_nontemporal_store(q0.x, &outB0[ko]);
        __builtin_nontemporal_store(q0.y, &outB1[ko]);
        __builtin_nontemporal_store(q1.x, &outB0[ko + 4 * HW]);
        __builtin_nontemporal_store(q1.y, &outB1[ko + 4 * HW]);
    }
}

extern "C" void kernel_launch(void* const* d_in, const int* in_sizes, int n_in,
                              void* d_out, int out_size, void* d_ws, size_t ws_size,
                              hipStream_t stream) {
    const float* x     = (const float*)d_in[0];
    const int*   idx_h = (const int*)d_in[1];
    const int*   idx_w = (const int*)d_in[2];
    const int*   idx_c = (const int*)d_in[3];
    const float* w0    = (const float*)d_in[4];
    const float* w1    = (const float*)d_in[5];
    const float* w2    = (const float*)d_in[6];
    const float* w3    = (const float*)d_in[7];
    float* out   = (float*)d_out;

    float* coefA = (float*)d_ws;                      // 15,360 B
    int*   loffA = (int*)((char*)d_ws + 16384);       // 4,096 B

    hipLaunchKernelGGL(prep_kernel, dim3(5), dim3(256), 0, stream,
                       idx_h, idx_w, idx_c, w0, w1, w2, w3, coefA, loffA);
    // 2 k-groups * 32 tiles * 8 batch-pairs = 512 blocks, XCD-pinned by bp
    hipLaunchKernelGGL(logic_conv_kernel, dim3(512), dim3(512), 0, stream,
                       x, loffA, coefA, out);
}

// Round 14
// 21.300 us; speedup vs baseline: 1.1752x; 1.1343x over previous
//
#include <hip/hip_runtime.h>
#include <hip/hip_bf16.h>

#define CIN 32
#define HW 64
#define KK 64
#define NLEAF 8
#define PADDING 2
#define TH 4                    // tile rows
#define TCW 16                  // tile cols
#define WR 8                    // window rows = TH + 4
#define WC 20                   // window cols = TCW + 4
#define WPOS (CIN * WR * WC)    // 5120 positions; f32x4 each -> 81920 B LDS

typedef float f32x2 __attribute__((ext_vector_type(2)));
typedef float f32x4 __attribute__((ext_vector_type(4)));

__device__ __constant__ float d_C[16][4] = {
    {0, 0, 0, 0},  {0, 0, 0, 1},  {0, 1, 0, -1}, {0, 1, 0, 0},
    {0, 0, 1, -1}, {0, 0, 1, 0},  {0, 1, 1, -2}, {0, 1, 1, -1},
    {1, -1, -1, 1},{1, -1, -1, 2},{1, 0, -1, 0}, {1, 0, -1, 1},
    {1, -1, 0, 0}, {1, -1, 0, 1}, {1, 0, 0, -1}, {1, 0, 0, 0}
};

// blocks 0..3: coefA[k*60 + node*4 + c]; block 4: loffA[k*16+n] = ELEMENT
// offset of leaf (c,dh,dw) in the f32x4-packed 32 x 8 x 20 window.
__global__ __launch_bounds__(256) void prep_kernel(
    const int* __restrict__ idx_h, const int* __restrict__ idx_w, const int* __restrict__ idx_c,
    const float* __restrict__ w0, const float* __restrict__ w1,
    const float* __restrict__ w2, const float* __restrict__ w3,
    float* __restrict__ coefA, int* __restrict__ loffA)
{
    if (blockIdx.x == 4) {
        int k = threadIdx.x;
        if (k < KK) {
            #pragma unroll
            for (int n = 0; n < 16; ++n) {
                int s = n >> 3, leaf = n & 7;
                int o = s * (KK * NLEAF) + k * NLEAF + leaf;
                loffA[k * 16 + n] = idx_c[o] * (WR * WC) + idx_h[o] * WC + idx_w[o];
            }
        }
        return;
    }
    int t = blockIdx.x * blockDim.x + threadIdx.x;
    if (t >= KK * 15) return;
    int k = t / 15, node = t % 15;
    const float* wp; int n;
    if (node < 8)       { wp = w0; n = node; }
    else if (node < 12) { wp = w1; n = node - 8; }
    else if (node < 14) { wp = w2; n = node - 12; }
    else                { wp = w3; n = 0; }
    const float* l = wp + (n * KK + k) * 16;
    float m = l[0];
    #pragma unroll
    for (int g = 1; g < 16; ++g) m = fmaxf(m, l[g]);
    float p[16], s = 0.f;
    #pragma unroll
    for (int g = 0; g < 16; ++g) { p[g] = expf(l[g] - m); s += p[g]; }
    float inv = 1.f / s;
    float c0 = 0, c1 = 0, c2 = 0, c3 = 0;
    #pragma unroll
    for (int g = 0; g < 16; ++g) {
        float w = p[g] * inv;
        c0 = fmaf(w, d_C[g][0], c0);
        c1 = fmaf(w, d_C[g][1], c1);
        c2 = fmaf(w, d_C[g][2], c2);
        c3 = fmaf(w, d_C[g][3], c3);
    }
    float* o = coefA + (k * 60 + node * 4);
    o[0] = c0; o[1] = c1; o[2] = c2; o[3] = c3;
}

__device__ __forceinline__ f32x2 bc(float s) { return (f32x2){s, s}; }
__device__ __forceinline__ f32x2 gate2(const float* c, f32x2 a, f32x2 b) {
    return __builtin_elementwise_fma(b,
               __builtin_elementwise_fma(a, bc(c[3]), bc(c[2])),
               __builtin_elementwise_fma(a, bc(c[1]), bc(c[0])));
}

// blockIdx = tile*8 + grp; grp = kh*4 + quad -> XCD slot (each (quad,kh) owns
// one XCD; that quad's 2.1 MB of x lives in its L2). 512 threads = 8 waves;
// wave w covers k in [kh*32 + 4w, +4). lane = pixel of the 4x16 tile;
// f32x4 = 4 batch images -> every gather is one ds_read_b128.
__global__ __launch_bounds__(512, 4) void logic_conv_kernel(
    const float* __restrict__ x, const int* __restrict__ loffA,
    const float* __restrict__ coefA, float* __restrict__ out)
{
    extern __shared__ f32x4 xt[];   // WPOS = 81920 B

    int tid  = threadIdx.x;
    int grp  = blockIdx.x & 7;
    int quad = grp & 3;
    int kh   = grp >> 2;
    int t    = blockIdx.x >> 3;        // tile 0..63
    int r0   = (t >> 2) * TH;
    int c0   = (t & 3) * TCW;

    const float* xb0 = x + (size_t)(4 * quad) * (CIN * HW * HW);
    const float* xb1 = xb0 + (CIN * HW * HW);
    const float* xb2 = xb1 + (CIN * HW * HW);
    const float* xb3 = xb2 + (CIN * HW * HW);

    // Stage packed padded 32x8x20 windows for 4 images (10 positions/thread).
    #pragma unroll
    for (int i = 0; i < 10; ++i) {
        int e  = tid + i * 512;
        int c  = e / (WR * WC);
        int r  = e - c * (WR * WC);
        int rr = r / WC;
        int cc = r - rr * WC;
        int ih = r0 + rr - PADDING, iw = c0 + cc - PADDING;
        f32x4 v = {0.f, 0.f, 0.f, 0.f};
        if ((unsigned)ih < HW && (unsigned)iw < HW) {
            int go = (c * HW + ih) * HW + iw;
            v.x = xb0[go];
            v.y = xb1[go];
            v.z = xb2[go];
            v.w = xb3[go];
        }
        xt[e] = v;
    }
    __syncthreads();

    int lane = tid & 63, wave = tid >> 6;
    int tr = lane >> 4, tc = lane & 15;
    int pxe   = tr * WC + tc;                  // element offset in window
    int pxout = (r0 + tr) * HW + (c0 + tc);    // output element offset
    float* outB0 = out + ((size_t)(4 * quad) << 18);
    float* outB1 = outB0 + (1 << 18);
    float* outB2 = outB1 + (1 << 18);
    float* outB3 = outB2 + (1 << 18);

    int kbase = __builtin_amdgcn_readfirstlane(kh * 32 + wave * 4);

    #pragma unroll 2
    for (int i = 0; i < 4; ++i) {
        int k = kbase + i;
        const int*   L = loffA + (k << 4);
        const float* C = coefA + k * 60;

        f32x2 gA[16], gB[16];
        #pragma unroll
        for (int n = 0; n < 16; ++n) {
            f32x4 gv = xt[L[n] + pxe];
            gA[n] = (f32x2){gv.x, gv.y};
            gB[n] = (f32x2){gv.z, gv.w};
        }

        f32x2 vA[8], vB[8];
        #pragma unroll
        for (int n = 0; n < 8; ++n) {
            vA[n] = gate2(C + 4 * n, gA[n], gA[8 + n]);
            vB[n] = gate2(C + 4 * n, gB[n], gB[8 + n]);
        }
        f32x2 uA[4], uB[4];
        #pragma unroll
        for (int n = 0; n < 4; ++n) {
            uA[n] = gate2(C + 32 + 4 * n, vA[2 * n], vA[2 * n + 1]);
            uB[n] = gate2(C + 32 + 4 * n, vB[2 * n], vB[2 * n + 1]);
        }
        f32x2 sA0 = gate2(C + 48, uA[0], uA[1]);
        f32x2 sA1 = gate2(C + 52, uA[2], uA[3]);
        f32x2 sB0 = gate2(C + 48, uB[0], uB[1]);
        f32x2 sB1 = gate2(C + 52, uB[2], uB[3]);
        f32x2 qA  = gate2(C + 56, sA0, sA1);
        f32x2 qB  = gate2(C + 56, sB0, sB1);

        int ko = (k << 12) + pxout;
        __builtin_nontemporal_store(qA.x, &outB0[ko]);
        __builtin_nontemporal_store(qA.y, &outB1[ko]);
        __builtin_nontemporal_store(qB.x, &outB2[ko]);
        __builtin_nontemporal_store(qB.y, &outB3[ko]);
    }
}

extern "C" void kernel_launch(void* const* d_in, const int* in_sizes, int n_in,
                              void* d_out, int out_size, void* d_ws, size_t ws_size,
                              hipStream_t stream) {
    const float* x     = (const float*)d_in[0];
    const int*   idx_h = (const int*)d_in[1];
    const int*   idx_w = (const int*)d_in[2];
    const int*   idx_c = (const int*)d_in[3];
    const float* w0    = (const float*)d_in[4];
    const float* w1    = (const float*)d_in[5];
    const float* w2    = (const float*)d_in[6];
    const float* w3    = (const float*)d_in[7];
    float* out   = (float*)d_out;

    float* coefA = (float*)d_ws;                      // 15,360 B
    int*   loffA = (int*)((char*)d_ws + 16384);       // 4,096 B

    hipLaunchKernelGGL(prep_kernel, dim3(5), dim3(256), 0, stream,
                       idx_h, idx_w, idx_c, w0, w1, w2, w3, coefA, loffA);
    // 64 tiles * (4 quads x 2 kh) = 512 blocks, 512 threads, 80 KB dynamic LDS
    hipLaunchKernelGGL(logic_conv_kernel, dim3(512), dim3(512),
                       WPOS * sizeof(f32x4), stream,
                       x, loffA, coefA, out);
}

// Round 15
// 21.261 us; speedup vs baseline: 1.1774x; 1.0019x over previous
//
#include <hip/hip_runtime.h>
#include <hip/hip_bf16.h>

#define CIN 32
#define HW 64
#define KK 64
#define NLEAF 8
#define PADDING 2
#define TH 4                    // tile rows
#define TCW 16                  // tile cols
#define WR 8                    // window rows = TH + 4
#define WC 20                   // window cols = TCW + 4
#define WPOS (CIN * WR * WC)    // 5120 positions; f32x4 each -> 81920 B LDS

typedef float f32x2 __attribute__((ext_vector_type(2)));
typedef float f32x4 __attribute__((ext_vector_type(4)));

__device__ __constant__ float d_C[16][4] = {
    {0, 0, 0, 0},  {0, 0, 0, 1},  {0, 1, 0, -1}, {0, 1, 0, 0},
    {0, 0, 1, -1}, {0, 0, 1, 0},  {0, 1, 1, -2}, {0, 1, 1, -1},
    {1, -1, -1, 1},{1, -1, -1, 2},{1, 0, -1, 0}, {1, 0, -1, 1},
    {1, -1, 0, 0}, {1, -1, 0, 1}, {1, 0, 0, -1}, {1, 0, 0, 0}
};

// Fully parallel prep: 4 blocks x 256 threads = 1024 threads.
// Every thread writes one loffA entry (1024 total) and, if tid<960, one
// coefA node (64k x 15 nodes). All loads issue concurrently -> ~1 round of
// memory latency instead of a serial per-thread loop.
__global__ __launch_bounds__(256) void prep_kernel(
    const int* __restrict__ idx_h, const int* __restrict__ idx_w, const int* __restrict__ idx_c,
    const float* __restrict__ w0, const float* __restrict__ w1,
    const float* __restrict__ w2, const float* __restrict__ w3,
    float* __restrict__ coefA, int* __restrict__ loffA)
{
    int tid = blockIdx.x * 256 + threadIdx.x;   // 0..1023

    // loffA[k*16+n]: element offset of leaf (c,dh,dw) in the 32x8x20 window
    {
        int k = tid >> 4, n = tid & 15;
        int s = n >> 3, leaf = n & 7;
        int o = s * (KK * NLEAF) + k * NLEAF + leaf;
        loffA[tid] = idx_c[o] * (WR * WC) + idx_h[o] * WC + idx_w[o];
        (void)k;
    }

    if (tid < KK * 15) {
        int k = tid / 15, node = tid % 15;
        const float* wp; int n;
        if (node < 8)       { wp = w0; n = node; }
        else if (node < 12) { wp = w1; n = node - 8; }
        else if (node < 14) { wp = w2; n = node - 12; }
        else                { wp = w3; n = 0; }
        const float4* lp = (const float4*)(wp + (size_t)(n * KK + k) * 16);
        float4 L0 = lp[0], L1 = lp[1], L2 = lp[2], L3 = lp[3];
        float l[16] = {L0.x, L0.y, L0.z, L0.w, L1.x, L1.y, L1.z, L1.w,
                       L2.x, L2.y, L2.z, L2.w, L3.x, L3.y, L3.z, L3.w};
        float m = l[0];
        #pragma unroll
        for (int g = 1; g < 16; ++g) m = fmaxf(m, l[g]);
        float p[16], s = 0.f;
        #pragma unroll
        for (int g = 0; g < 16; ++g) { p[g] = __expf(l[g] - m); s += p[g]; }
        float inv = 1.f / s;
        float c0 = 0, c1 = 0, c2 = 0, c3 = 0;
        #pragma unroll
        for (int g = 0; g < 16; ++g) {
            float w = p[g] * inv;
            c0 = fmaf(w, d_C[g][0], c0);
            c1 = fmaf(w, d_C[g][1], c1);
            c2 = fmaf(w, d_C[g][2], c2);
            c3 = fmaf(w, d_C[g][3], c3);
        }
        float* o = coefA + (k * 60 + node * 4);
        o[0] = c0; o[1] = c1; o[2] = c2; o[3] = c3;
    }
}

__device__ __forceinline__ f32x2 bc(float s) { return (f32x2){s, s}; }
__device__ __forceinline__ f32x2 gate2(const float* c, f32x2 a, f32x2 b) {
    return __builtin_elementwise_fma(b,
               __builtin_elementwise_fma(a, bc(c[3]), bc(c[2])),
               __builtin_elementwise_fma(a, bc(c[1]), bc(c[0])));
}

// blockIdx = tile*8 + grp; grp = kh*4 + quad -> XCD slot (each (quad,kh) owns
// one XCD; that quad's 2.1 MB of x lives in its L2). 512 threads = 8 waves;
// wave w covers k in [kh*32 + 4w, +4). lane = pixel of the 4x16 tile;
// f32x4 = 4 batch images -> every gather is one ds_read_b128.
__global__ __launch_bounds__(512, 4) void logic_conv_kernel(
    const float* __restrict__ x, const int* __restrict__ loffA,
    const float* __restrict__ coefA, float* __restrict__ out)
{
    extern __shared__ f32x4 xt[];   // WPOS = 81920 B

    int tid  = threadIdx.x;
    int grp  = blockIdx.x & 7;
    int quad = grp & 3;
    int kh   = grp >> 2;
    int t    = blockIdx.x >> 3;        // tile 0..63
    int r0   = (t >> 2) * TH;
    int c0   = (t & 3) * TCW;

    const float* xb0 = x + (size_t)(4 * quad) * (CIN * HW * HW);
    const float* xb1 = xb0 + (CIN * HW * HW);
    const float* xb2 = xb1 + (CIN * HW * HW);
    const float* xb3 = xb2 + (CIN * HW * HW);

    // Stage packed padded 32x8x20 windows for 4 images (10 positions/thread).
    #pragma unroll
    for (int i = 0; i < 10; ++i) {
        int e  = tid + i * 512;
        int c  = e / (WR * WC);
        int r  = e - c * (WR * WC);
        int rr = r / WC;
        int cc = r - rr * WC;
        int ih = r0 + rr - PADDING, iw = c0 + cc - PADDING;
        f32x4 v = {0.f, 0.f, 0.f, 0.f};
        if ((unsigned)ih < HW && (unsigned)iw < HW) {
            int go = (c * HW + ih) * HW + iw;
            v.x = xb0[go];
            v.y = xb1[go];
            v.z = xb2[go];
            v.w = xb3[go];
        }
        xt[e] = v;
    }
    __syncthreads();

    int lane = tid & 63, wave = tid >> 6;
    int tr = lane >> 4, tc = lane & 15;
    int pxe   = tr * WC + tc;                  // element offset in window
    int pxout = (r0 + tr) * HW + (c0 + tc);    // output element offset
    float* outB0 = out + ((size_t)(4 * quad) << 18);
    float* outB1 = outB0 + (1 << 18);
    float* outB2 = outB1 + (1 << 18);
    float* outB3 = outB2 + (1 << 18);

    int kbase = __builtin_amdgcn_readfirstlane(kh * 32 + wave * 4);

    #pragma unroll 2
    for (int i = 0; i < 4; ++i) {
        int k = kbase + i;
        const int*   L = loffA + (k << 4);
        const float* C = coefA + k * 60;

        f32x2 gA[16], gB[16];
        #pragma unroll
        for (int n = 0; n < 16; ++n) {
            f32x4 gv = xt[L[n] + pxe];
            gA[n] = (f32x2){gv.x, gv.y};
            gB[n] = (f32x2){gv.z, gv.w};
        }

        f32x2 vA[8], vB[8];
        #pragma unroll
        for (int n = 0; n < 8; ++n) {
            vA[n] = gate2(C + 4 * n, gA[n], gA[8 + n]);
            vB[n] = gate2(C + 4 * n, gB[n], gB[8 + n]);
        }
        f32x2 uA[4], uB[4];
        #pragma unroll
        for (int n = 0; n < 4; ++n) {
            uA[n] = gate2(C + 32 + 4 * n, vA[2 * n], vA[2 * n + 1]);
            uB[n] = gate2(C + 32 + 4 * n, vB[2 * n], vB[2 * n + 1]);
        }
        f32x2 sA0 = gate2(C + 48, uA[0], uA[1]);
        f32x2 sA1 = gate2(C + 52, uA[2], uA[3]);
        f32x2 sB0 = gate2(C + 48, uB[0], uB[1]);
        f32x2 sB1 = gate2(C + 52, uB[2], uB[3]);
        f32x2 qA  = gate2(C + 56, sA0, sA1);
        f32x2 qB  = gate2(C + 56, sB0, sB1);

        int ko = (k << 12) + pxout;
        __builtin_nontemporal_store(qA.x, &outB0[ko]);
        __builtin_nontemporal_store(qA.y, &outB1[ko]);
        __builtin_nontemporal_store(qB.x, &outB2[ko]);
        __builtin_nontemporal_store(qB.y, &outB3[ko]);
    }
}

extern "C" void kernel_launch(void* const* d_in, const int* in_sizes, int n_in,
                              void* d_out, int out_size, void* d_ws, size_t ws_size,
                              hipStream_t stream) {
    const float* x     = (const float*)d_in[0];
    const int*   idx_h = (const int*)d_in[1];
    const int*   idx_w = (const int*)d_in[2];
    const int*   idx_c = (const int*)d_in[3];
    const float* w0    = (const float*)d_in[4];
    const float* w1    = (const float*)d_in[5];
    const float* w2    = (const float*)d_in[6];
    const float* w3    = (const float*)d_in[7];
    float* out   = (float*)d_out;

    float* coefA = (float*)d_ws;                      // 15,360 B
    int*   loffA = (int*)((char*)d_ws + 16384);       // 4,096 B

    hipLaunchKernelGGL(prep_kernel, dim3(4), dim3(256), 0, stream,
                       idx_h, idx_w, idx_c, w0, w1, w2, w3, coefA, loffA);
    // 64 tiles * (4 quads x 2 kh) = 512 blocks, 512 threads, 80 KB dynamic LDS
    hipLaunchKernelGGL(logic_conv_kernel, dim3(512), dim3(512),
                       WPOS * sizeof(f32x4), stream,
                       x, loffA, coefA, out);
}